// Round 9
// baseline (268.714 us; speedup 1.0000x reference)
//
#include <hip/hip_runtime.h>
#include <hip/hip_cooperative_groups.h>

namespace cg = cooperative_groups;

// Problem constants
#define HDIM 64
#define LSEQ 2048
#define BATCH 16
#define LN_EPS 1e-5f
#define D_EPS 1e-6f
#define CHUNK 16
#define NCHUNK 128   // 2048 solve slots (incl. 1 zero-padded) / 16
#define NSEG 16
#define CPS 8        // chunks per segment

typedef unsigned short u16;
typedef unsigned int   u32;

__device__ __forceinline__ float bf2f(u16 v) {
    return __uint_as_float(((u32)v) << 16);
}
__device__ __forceinline__ u16 f2bf(float f) {   // round-to-nearest-even
    u32 u = __float_as_uint(f);
    return (u16)((u + 0x7FFFu + ((u >> 16) & 1u)) >> 16);
}

// Shared-memory overlay offsets (bytes). Max live size = phase A = 123488 B.
// Phase A (preprocess):
#define A_SW1   0        // f32[64*132]  33792
#define A_SW2   33792    // f32[128*68]  34816
#define A_ET    68608    // f32[64*68]   17408
#define A_HIDT  86016    // f32[128*68]  34816
#define A_RED1  120832   // f32[4*66]    1056
#define A_RED2  121888   // f32[4*66]    1056
#define A_SMU   122944   // f32[66]      272 (padded)
#define A_SRSTD 123216   // f32[66]      272
#define SMEM_BYTES 123488
// Phase B (compose):
#define B_S     0        // f32[64*68]   17408
#define B_V     17408    // f32[64*68]   17408
#define B_K     34816    // f32[16*68]   4352
#define B_BM    39168    // f32[16*68]   4352
#define B_Z     43520    // f32[16*68]   4352
#define B_GM    47872    // f32[16*17]   1088
#define B_IVD   48960    // f32[16]      64
// Phase C (final):
#define C_PSUM  0        // f32[4*72]    1152
#define C_RL    1152     // f32[64]      256
#define C_CS    1408     // f32[64]      256
#define C_RS    1664     // f32[64]      256

// ---------------------------------------------------------------------------
// One cooperative kernel, 256 blocks x 256 threads (1 block/CU; 123 KB LDS
// forces sole residency, so all blocks are co-resident and grid.sync is safe).
// Phase A: preprocess (2 x 64-token tiles/block; weights staged once).
// Phase B: segment composition (R5 math, Zt computed inline -> less LDS).
// Phase C: serial segment pass + output projection (blocks 0..15).
// ---------------------------------------------------------------------------
__global__ __launch_bounds__(256, 1) void fused_kernel(
    const int* __restrict__ seq, const float* __restrict__ embed,
    const float* __restrict__ W1, const float* __restrict__ b1,
    const float* __restrict__ W2, const float* __restrict__ b2,
    const float* __restrict__ gamma, const float* __restrict__ beta,
    const float* __restrict__ Wr, const float* __restrict__ br,
    const float* __restrict__ Wo, const float* __restrict__ bo,
    u16* __restrict__ h_ws, float* __restrict__ invd_ws,
    u32* __restrict__ PK, float* __restrict__ out)
{
    cg::grid_group grid = cg::this_grid();
    __shared__ __align__(16) char smem[SMEM_BYTES];
    const int t = threadIdx.x;

    // =========================== Phase A: preprocess =======================
    {
        float* sW1   = (float*)(smem + A_SW1);
        float* sW2   = (float*)(smem + A_SW2);
        float* eT    = (float*)(smem + A_ET);
        float* hidT  = (float*)(smem + A_HIDT);
        float* red1  = (float*)(smem + A_RED1);
        float* red2  = (float*)(smem + A_RED2);
        float* smu   = (float*)(smem + A_SMU);
        float* srstd = (float*)(smem + A_SRSTD);

        // stage W1 (64x128, stride 132) and W2 (128x64, stride 68) once
        {
            const float4* s1 = (const float4*)W1;   // 2048 float4
#pragma unroll
            for (int q = 0; q < 8; ++q) {
                const int m = t + 256 * q;
                const int row = m >> 5, col = m & 31;
                *(float4*)&sW1[row * 132 + col * 4] = s1[m];
            }
            const float4* s2 = (const float4*)W2;   // 2048 float4
#pragma unroll
            for (int q = 0; q < 8; ++q) {
                const int m = t + 256 * q;
                const int row = m >> 4, col = m & 15;
                *(float4*)&sW2[row * 68 + col * 4] = s2[m];
            }
        }

        for (int it = 0; it < 2; ++it) {
            const int tok0 = blockIdx.x * 128 + it * 64;
            __syncthreads();   // W staging (it=0) / prior tile reads (it=1)

            // stage embeddings transposed: thread (tk = t>>2, p = t&3)
            {
                const int tk = t >> 2, p = t & 3;
                const int v = seq[tok0 + tk];
                const float* er = embed + v * HDIM + 16 * p;
#pragma unroll
                for (int q = 0; q < 4; ++q) {
                    const float4 ev = *(const float4*)(er + 4 * q);
                    const int d = 16 * p + 4 * q;
                    eT[(d + 0) * 68 + tk] = ev.x;
                    eT[(d + 1) * 68 + tk] = ev.y;
                    eT[(d + 2) * 68 + tk] = ev.z;
                    eT[(d + 3) * 68 + tk] = ev.w;
                }
            }
            __syncthreads();

            const int r = t >> 4;   // token quad
            const int c = t & 15;   // out quad

            // MLP1: hid = relu(e W1 + b1)
            {
                float acc0[4][4], acc1[4][4];
#pragma unroll
                for (int o = 0; o < 4; ++o) {
                    const float bA = b1[4 * c + o];
                    const float bB = b1[64 + 4 * c + o];
#pragma unroll
                    for (int j = 0; j < 4; ++j) { acc0[j][o] = bA; acc1[j][o] = bB; }
                }
                for (int k = 0; k < 64; ++k) {
                    const float4 ev = *(const float4*)&eT[k * 68 + 4 * r];
                    const float4 wa = *(const float4*)&sW1[k * 132 + 4 * c];
                    const float4 wb = *(const float4*)&sW1[k * 132 + 64 + 4 * c];
                    const float e4[4] = {ev.x, ev.y, ev.z, ev.w};
                    const float a4[4] = {wa.x, wa.y, wa.z, wa.w};
                    const float b4[4] = {wb.x, wb.y, wb.z, wb.w};
#pragma unroll
                    for (int j = 0; j < 4; ++j)
#pragma unroll
                        for (int o = 0; o < 4; ++o) {
                            acc0[j][o] = fmaf(e4[j], a4[o], acc0[j][o]);
                            acc1[j][o] = fmaf(e4[j], b4[o], acc1[j][o]);
                        }
                }
#pragma unroll
                for (int o = 0; o < 4; ++o)
#pragma unroll
                    for (int j = 0; j < 4; ++j) {
                        hidT[(4 * c + o) * 68 + 4 * r + j]      = fmaxf(acc0[j][o], 0.f);
                        hidT[(64 + 4 * c + o) * 68 + 4 * r + j] = fmaxf(acc1[j][o], 0.f);
                    }
            }
            __syncthreads();

            // MLP2: ff = hid W2 + b2; x = e + ff in place into eT
            {
                float acc[4][4];
#pragma unroll
                for (int o = 0; o < 4; ++o) {
                    const float bv = b2[4 * c + o];
#pragma unroll
                    for (int j = 0; j < 4; ++j) acc[j][o] = bv;
                }
                for (int k = 0; k < 128; ++k) {
                    const float4 hv = *(const float4*)&hidT[k * 68 + 4 * r];
                    const float4 wv = *(const float4*)&sW2[k * 68 + 4 * c];
                    const float h4[4] = {hv.x, hv.y, hv.z, hv.w};
                    const float w4[4] = {wv.x, wv.y, wv.z, wv.w};
#pragma unroll
                    for (int j = 0; j < 4; ++j)
#pragma unroll
                        for (int o = 0; o < 4; ++o)
                            acc[j][o] = fmaf(h4[j], w4[o], acc[j][o]);
                }
#pragma unroll
                for (int o = 0; o < 4; ++o)
#pragma unroll
                    for (int j = 0; j < 4; ++j)
                        eT[(4 * c + o) * 68 + (4 * r + j)] += acc[j][o];
            }
            __syncthreads();

            // LN stats
            {
                const int tk = t & 63, p = t >> 6;
                float s = 0.f, q = 0.f;
#pragma unroll
                for (int i = 0; i < 16; ++i) {
                    const float x = eT[(16 * p + i) * 68 + tk];
                    s += x;
                    q = fmaf(x, x, q);
                }
                red1[p * 66 + tk] = s;
                red2[p * 66 + tk] = q;
            }
            __syncthreads();
            if (t < 64) {
                const float s  = ((red1[0 * 66 + t] + red1[1 * 66 + t]) + (red1[2 * 66 + t] + red1[3 * 66 + t]));
                const float qq = ((red2[0 * 66 + t] + red2[1 * 66 + t]) + (red2[2 * 66 + t] + red2[3 * 66 + t]));
                const float mu  = s * (1.0f / 64.0f);
                const float var = qq * (1.0f / 64.0f) - mu * mu;
                smu[t]   = mu;
                srstd[t] = 1.0f / sqrtf(var + LN_EPS);
            }
            __syncthreads();

            // normalize, round bf16, write h; hh over ROUNDED values
            {
                const int tk = t >> 2, p = t & 3;
                const float mu = smu[tk], rstd = srstd[tk];
                float hh = 0.f;
                u32 pw[8];
#pragma unroll
                for (int i2 = 0; i2 < 8; ++i2) {
                    const int d = 16 * p + 2 * i2;
                    const float x0 = eT[(d + 0) * 68 + tk];
                    const float x1 = eT[(d + 1) * 68 + tk];
                    const float o0 = (x0 - mu) * rstd * gamma[d + 0] + beta[d + 0];
                    const float o1 = (x1 - mu) * rstd * gamma[d + 1] + beta[d + 1];
                    const u16 r0 = f2bf(o0), r1 = f2bf(o1);
                    const float q0f = bf2f(r0), q1f = bf2f(r1);
                    hh = fmaf(q0f, q0f, hh);
                    hh = fmaf(q1f, q1f, hh);
                    pw[i2] = (u32)r0 | ((u32)r1 << 16);
                }
                uint4* hp = (uint4*)(h_ws + (size_t)(tok0 + tk) * HDIM + 16 * p);
                hp[0] = make_uint4(pw[0], pw[1], pw[2], pw[3]);
                hp[1] = make_uint4(pw[4], pw[5], pw[6], pw[7]);
                red1[p * 66 + tk] = hh;
            }
            __syncthreads();
            if (t < 64) {
                const float hh = ((red1[0 * 66 + t] + red1[1 * 66 + t]) + (red1[2 * 66 + t] + red1[3 * 66 + t]));
                invd_ws[tok0 + t] = 1.0f / (hh + D_EPS);
            }
        }
    }

    __threadfence();
    grid.sync();

    // ========================= Phase B: compose ============================
    {
        float* S     = (float*)(smem + B_S);
        float* V     = (float*)(smem + B_V);
        float* K     = (float*)(smem + B_K);
        float* Bm    = (float*)(smem + B_BM);
        float* Z     = (float*)(smem + B_Z);
        float* Gm    = (float*)(smem + B_GM);
        float* ivd_s = (float*)(smem + B_IVD);

        const int b = blockIdx.x >> 4;
        const int s = blockIdx.x & 15;
        const u16*   hbase = h_ws + (size_t)b * LSEQ * HDIM;
        const float* dbase = invd_ws + b * LSEQ;

        // init S = I, V = 0
        for (int idx = t; idx < 64 * 64; idx += 256) {
            const int m = idx >> 6, n = idx & 63;
            S[m * 68 + n] = (m == n) ? 1.0f : 0.0f;
            V[m * 68 + n] = 0.0f;
        }

        for (int cc = 0; cc < CPS; ++cc) {
            const int c = s * CPS + cc;
            __syncthreads();   // staging vs previous phase reads / init

            // stage K (bf16 -> f32) and ivd
            {
                const int j  = t >> 4;
                const int n0 = (t & 15) * 4;
                const int sigma = 16 * c + j;
                float4 kv = make_float4(0.f, 0.f, 0.f, 0.f);
                if (sigma > 0) {
                    const ushort4 raw = *(const ushort4*)(hbase + (size_t)(2047 - sigma) * HDIM + n0);
                    kv.x = bf2f(raw.x); kv.y = bf2f(raw.y); kv.z = bf2f(raw.z); kv.w = bf2f(raw.w);
                }
                *(float4*)&K[j * 68 + n0] = kv;
                if (t < 16) ivd_s[t] = dbase[2047 - (16 * c + t)];
            }
            __syncthreads();

            // Gram: Gm[i][j] = (k_i . k_j) * ivd_j, i > j
            {
                const int i = t >> 4, j = t & 15;
                if (i > j) {
                    float acc = 0.f;
#pragma unroll
                    for (int m = 0; m < 64; m += 4) {
                        const float4 a  = *(const float4*)&K[i * 68 + m];
                        const float4 bb = *(const float4*)&K[j * 68 + m];
                        acc += a.x * bb.x + a.y * bb.y + a.z * bb.z + a.w * bb.w;
                    }
                    Gm[i * 17 + j] = acc * ivd_s[j];
                }
            }
            __syncthreads();

            // B: forward substitution L B = K (wave 0)
            if (t < 64) {
                const int n = t;
                float Breg[16];
#pragma unroll
                for (int i = 0; i < 16; ++i) {
                    float acc = K[i * 68 + n];
#pragma unroll
                    for (int j = 0; j < 16; ++j)
                        if (j < i) acc = fmaf(-Gm[i * 17 + j], Breg[j], acc);
                    Breg[i] = acc;
                    Bm[i * 68 + n] = acc;
                }
            }
            __syncthreads();

            // Z = B S  (Zt no longer materialized)
            {
                const int i  = t & 15;
                const int n0 = (t >> 4) * 4;
                float4 z = make_float4(0.f, 0.f, 0.f, 0.f);
#pragma unroll
                for (int mq = 0; mq < 16; ++mq) {
                    const float4 bq = *(const float4*)&Bm[i * 68 + mq * 4];
                    const float4 s0 = *(const float4*)&S[(mq * 4 + 0) * 68 + n0];
                    const float4 s1 = *(const float4*)&S[(mq * 4 + 1) * 68 + n0];
                    const float4 s2 = *(const float4*)&S[(mq * 4 + 2) * 68 + n0];
                    const float4 s3 = *(const float4*)&S[(mq * 4 + 3) * 68 + n0];
                    z.x = fmaf(bq.x, s0.x, fmaf(bq.y, s1.x, fmaf(bq.z, s2.x, fmaf(bq.w, s3.x, z.x))));
                    z.y = fmaf(bq.x, s0.y, fmaf(bq.y, s1.y, fmaf(bq.z, s2.y, fmaf(bq.w, s3.y, z.y))));
                    z.z = fmaf(bq.x, s0.z, fmaf(bq.y, s1.z, fmaf(bq.z, s2.z, fmaf(bq.w, s3.z, z.z))));
                    z.w = fmaf(bq.x, s0.w, fmaf(bq.y, s1.w, fmaf(bq.z, s2.w, fmaf(bq.w, s3.w, z.w))));
                }
                *(float4*)&Z[i * 68 + n0] = z;
            }
            __syncthreads();

            // S -= K^T (ivd_j * Z) ; V += K^T Z   (ztq computed inline)
            {
                const int n0 = (t & 15) * 4;
                const int mh = t >> 4;
                float iv16[16];
#pragma unroll
                for (int q4 = 0; q4 < 4; ++q4) {
                    const float4 v4 = *(const float4*)&ivd_s[4 * q4];
                    iv16[4*q4+0] = v4.x; iv16[4*q4+1] = v4.y;
                    iv16[4*q4+2] = v4.z; iv16[4*q4+3] = v4.w;
                }
                float4 sacc[4], vacc[4];
#pragma unroll
                for (int p = 0; p < 4; ++p) {
                    sacc[p] = *(float4*)&S[(mh + 16 * p) * 68 + n0];
                    vacc[p] = *(float4*)&V[(mh + 16 * p) * 68 + n0];
                }
#pragma unroll
                for (int j = 0; j < 16; ++j) {
                    const float4 zq = *(const float4*)&Z[j * 68 + n0];
                    const float iv = iv16[j];
                    float4 ztq;
                    ztq.x = zq.x * iv; ztq.y = zq.y * iv;
                    ztq.z = zq.z * iv; ztq.w = zq.w * iv;
                    const float k0 = K[j * 68 + mh];
                    const float k1 = K[j * 68 + mh + 16];
                    const float k2 = K[j * 68 + mh + 32];
                    const float k3 = K[j * 68 + mh + 48];
                    vacc[0].x = fmaf(k0, zq.x, vacc[0].x); vacc[0].y = fmaf(k0, zq.y, vacc[0].y);
                    vacc[0].z = fmaf(k0, zq.z, vacc[0].z); vacc[0].w = fmaf(k0, zq.w, vacc[0].w);
                    vacc[1].x = fmaf(k1, zq.x, vacc[1].x); vacc[1].y = fmaf(k1, zq.y, vacc[1].y);
                    vacc[1].z = fmaf(k1, zq.z, vacc[1].z); vacc[1].w = fmaf(k1, zq.w, vacc[1].w);
                    vacc[2].x = fmaf(k2, zq.x, vacc[2].x); vacc[2].y = fmaf(k2, zq.y, vacc[2].y);
                    vacc[2].z = fmaf(k2, zq.z, vacc[2].z); vacc[2].w = fmaf(k2, zq.w, vacc[2].w);
                    vacc[3].x = fmaf(k3, zq.x, vacc[3].x); vacc[3].y = fmaf(k3, zq.y, vacc[3].y);
                    vacc[3].z = fmaf(k3, zq.z, vacc[3].z); vacc[3].w = fmaf(k3, zq.w, vacc[3].w);
                    sacc[0].x = fmaf(-k0, ztq.x, sacc[0].x); sacc[0].y = fmaf(-k0, ztq.y, sacc[0].y);
                    sacc[0].z = fmaf(-k0, ztq.z, sacc[0].z); sacc[0].w = fmaf(-k0, ztq.w, sacc[0].w);
                    sacc[1].x = fmaf(-k1, ztq.x, sacc[1].x); sacc[1].y = fmaf(-k1, ztq.y, sacc[1].y);
                    sacc[1].z = fmaf(-k1, ztq.z, sacc[1].z); sacc[1].w = fmaf(-k1, ztq.w, sacc[1].w);
                    sacc[2].x = fmaf(-k2, ztq.x, sacc[2].x); sacc[2].y = fmaf(-k2, ztq.y, sacc[2].y);
                    sacc[2].z = fmaf(-k2, ztq.z, sacc[2].z); sacc[2].w = fmaf(-k2, ztq.w, sacc[2].w);
                    sacc[3].x = fmaf(-k3, ztq.x, sacc[3].x); sacc[3].y = fmaf(-k3, ztq.y, sacc[3].y);
                    sacc[3].z = fmaf(-k3, ztq.z, sacc[3].z); sacc[3].w = fmaf(-k3, ztq.w, sacc[3].w);
                }
#pragma unroll
                for (int p = 0; p < 4; ++p) {
                    *(float4*)&S[(mh + 16 * p) * 68 + n0] = sacc[p];
                    *(float4*)&V[(mh + 16 * p) * 68 + n0] = vacc[p];
                }
            }
        }
        __syncthreads();

        // writeback: pk[j*64+i] = pack(bf16(S[i][j]), bf16(V[i][j]))
        u32* pk = PK + ((size_t)(b * NSEG + s) << 12);
        for (int idx = t; idx < 4096; idx += 256) {
            const int j = idx >> 6, i = idx & 63;
            const u32 sb = ((u32)f2bf(S[i * 68 + j])) << 16;
            const u32 vb = (u32)f2bf(V[i * 68 + j]);
            pk[idx] = sb | vb;
        }
    }

    __threadfence();
    grid.sync();

    // ========================== Phase C: final =============================
    if (blockIdx.x < BATCH) {
        float* psum = (float*)(smem + C_PSUM);   // [4][72]
        float* rl   = (float*)(smem + C_RL);
        float* cs   = (float*)(smem + C_CS);
        float* rs   = (float*)(smem + C_RS);

        const int b    = blockIdx.x;
        const int lane = t & 63;
        const int p    = t >> 6;

        rl[lane] = bf2f(h_ws[(size_t)b * LSEQ * HDIM + (size_t)2047 * HDIM + lane]);

        float ctxp = 0.f;
        u32 cur[16], nxt[16];
        {
            const u32* pk0 = PK + ((size_t)(b * NSEG + 0) << 12);
#pragma unroll
            for (int jj = 0; jj < 16; ++jj)
                cur[jj] = pk0[(p * 16 + jj) * 64 + lane];
        }
        __syncthreads();

        for (int s = 0; s < NSEG; ++s) {
            const int sn = (s + 1 < NSEG) ? s + 1 : s;
            const u32* pkn = PK + ((size_t)(b * NSEG + sn) << 12);
#pragma unroll
            for (int jj = 0; jj < 16; ++jj)
                nxt[jj] = pkn[(p * 16 + jj) * 64 + lane];

            float accr = 0.f;
#pragma unroll
            for (int jj = 0; jj < 16; ++jj) {
                const u32 pv = cur[jj];
                const float Sv = __uint_as_float(pv & 0xFFFF0000u);
                const float Vv = __uint_as_float(pv << 16);
                const float rj = rl[p * 16 + jj];
                accr = fmaf(Sv, rj, accr);
                ctxp = fmaf(Vv, rj, ctxp);
            }
            psum[p * 72 + lane] = accr;
            __syncthreads();
            const float rn = (psum[0 * 72 + lane] + psum[1 * 72 + lane])
                           + (psum[2 * 72 + lane] + psum[3 * 72 + lane]);
            __syncthreads();
            rl[lane] = rn;

#pragma unroll
            for (int jj = 0; jj < 16; ++jj) cur[jj] = nxt[jj];
        }

        psum[p * 72 + lane] = ctxp;
        __syncthreads();
        if (t < 64)
            cs[t] = (psum[0 * 72 + t] + psum[1 * 72 + t]) + (psum[2 * 72 + t] + psum[3 * 72 + t]);
        __syncthreads();

        float rv = (p == 0) ? br[lane] : 0.f;
#pragma unroll
        for (int i = 0; i < 16; ++i)
            rv = fmaf(cs[p * 16 + i], Wr[(p * 16 + i) * HDIM + lane], rv);
        psum[p * 72 + lane] = rv;
        __syncthreads();
        if (t < 64)
            rs[t] = (psum[0 * 72 + t] + psum[1 * 72 + t]) + (psum[2 * 72 + t] + psum[3 * 72 + t]);
        __syncthreads();

        float ov = (p == 0) ? bo[lane] : 0.f;
#pragma unroll
        for (int i = 0; i < 16; ++i)
            ov = fmaf(rs[p * 16 + i], Wo[(p * 16 + i) * HDIM + lane], ov);
        psum[p * 72 + lane] = ov;
        __syncthreads();
        if (t < 64)
            out[(size_t)b * HDIM + t] = (psum[0 * 72 + t] + psum[1 * 72 + t]) + (psum[2 * 72 + t] + psum[3 * 72 + t]);
    }
}

// ---------------------------------------------------------------------------
extern "C" void kernel_launch(void* const* d_in, const int* in_sizes, int n_in,
                              void* d_out, int out_size, void* d_ws, size_t ws_size,
                              hipStream_t stream)
{
    const int*   seq   = (const int*)  d_in[0];
    const float* embed = (const float*)d_in[1];
    const float* W1    = (const float*)d_in[2];
    const float* b1    = (const float*)d_in[3];
    const float* W2    = (const float*)d_in[4];
    const float* b2    = (const float*)d_in[5];
    const float* gamma = (const float*)d_in[6];
    const float* beta  = (const float*)d_in[7];
    const float* Wr    = (const float*)d_in[8];
    const float* br    = (const float*)d_in[9];
    const float* Wo    = (const float*)d_in[10];
    const float* bo    = (const float*)d_in[11];

    u16*   h_ws    = (u16*)d_ws;                                   // 4 MB
    float* invd_ws = (float*)(h_ws + (size_t)BATCH * LSEQ * HDIM); // 128 KB
    u32*   pk_ws   = (u32*)(invd_ws + (size_t)BATCH * LSEQ);       // 4 MB
    float* outp    = (float*)d_out;

    void* kargs[] = {
        (void*)&seq, (void*)&embed, (void*)&W1, (void*)&b1, (void*)&W2,
        (void*)&b2, (void*)&gamma, (void*)&beta, (void*)&Wr, (void*)&br,
        (void*)&Wo, (void*)&bo, (void*)&h_ws, (void*)&invd_ws,
        (void*)&pk_ws, (void*)&outp
    };
    hipLaunchCooperativeKernel((const void*)fused_kernel, dim3(256), dim3(256),
                               kargs, 0, stream);
}

// Round 10
// 144.506 us; speedup vs baseline: 1.8595x; 1.8595x over previous
//
#include <hip/hip_runtime.h>

// Problem constants
#define HDIM 64
#define LSEQ 2048
#define BATCH 16
#define LN_EPS 1e-5f
#define D_EPS 1e-6f
#define CHUNK 16
#define NCHUNK 128   // 2048 solve slots (incl. 1 zero-padded) / 16
#define NSEG 32      // segments per batch (R10: was 16)
#define CPS 4        // chunks per segment (R10: was 8)

typedef unsigned short u16;
typedef unsigned int   u32;

__device__ __forceinline__ float bf2f(u16 v) {
    return __uint_as_float(((u32)v) << 16);
}
__device__ __forceinline__ u16 f2bf(float f) {   // round-to-nearest-even
    u32 u = __float_as_uint(f);
    return (u16)((u + 0x7FFFu + ((u >> 16) & 1u)) >> 16);
}

// ---------------------------------------------------------------------------
// Kernel 1: preprocessing as a register-blocked tiled GEMM (unchanged from
// rounds 7/8 — controlled). 64 tokens/block, 512 blocks, 256 threads.
// ---------------------------------------------------------------------------
__global__ __launch_bounds__(256, 1) void preprocess_kernel(
    const int* __restrict__ seq, const float* __restrict__ embed,
    const float* __restrict__ W1, const float* __restrict__ b1,
    const float* __restrict__ W2, const float* __restrict__ b2,
    const float* __restrict__ gamma, const float* __restrict__ beta,
    u16* __restrict__ h_out, float* __restrict__ invd_out)
{
    __shared__ float sW1[64 * 132];    // [k][out], stride 132 (33 float4)
    __shared__ float sW2[128 * 68];    // [k][out], stride 68
    __shared__ float eT[64 * 68];      // [dim][tok] -> becomes x = e+ff in place
    __shared__ float hidT[128 * 68];   // [hid][tok], relu'd MLP1 output
    __shared__ float red1[4][66], red2[4][66];
    __shared__ float smu[66], srstd[66];

    const int t    = threadIdx.x;
    const int tok0 = blockIdx.x * 64;

    // ---- stage W1 (64x128) and W2 (128x64) ----
    {
        const float4* s1 = (const float4*)W1;   // 2048 float4
#pragma unroll
        for (int q = 0; q < 8; ++q) {
            const int m = t + 256 * q;
            const int row = m >> 5, col = m & 31;
            *(float4*)&sW1[row * 132 + col * 4] = s1[m];
        }
        const float4* s2 = (const float4*)W2;   // 2048 float4
#pragma unroll
        for (int q = 0; q < 8; ++q) {
            const int m = t + 256 * q;
            const int row = m >> 4, col = m & 15;
            *(float4*)&sW2[row * 68 + col * 4] = s2[m];
        }
    }
    // ---- stage embeddings transposed: thread (tk = t>>2, p = t&3) ----
    {
        const int tk = t >> 2, p = t & 3;
        const int v = seq[tok0 + tk];
        const float* er = embed + v * HDIM + 16 * p;
#pragma unroll
        for (int q = 0; q < 4; ++q) {
            const float4 ev = *(const float4*)(er + 4 * q);
            const int d = 16 * p + 4 * q;
            eT[(d + 0) * 68 + tk] = ev.x;
            eT[(d + 1) * 68 + tk] = ev.y;
            eT[(d + 2) * 68 + tk] = ev.z;
            eT[(d + 3) * 68 + tk] = ev.w;
        }
    }
    __syncthreads();

    const int r = t >> 4;   // token quad: toks 4r..4r+3
    const int c = t & 15;   // out quad

    // ---- MLP1: hid = relu(e W1 + b1) ----
    {
        float acc0[4][4], acc1[4][4];
#pragma unroll
        for (int o = 0; o < 4; ++o) {
            const float bA = b1[4 * c + o];
            const float bB = b1[64 + 4 * c + o];
#pragma unroll
            for (int j = 0; j < 4; ++j) { acc0[j][o] = bA; acc1[j][o] = bB; }
        }
        for (int k = 0; k < 64; ++k) {
            const float4 ev = *(const float4*)&eT[k * 68 + 4 * r];
            const float4 wa = *(const float4*)&sW1[k * 132 + 4 * c];
            const float4 wb = *(const float4*)&sW1[k * 132 + 64 + 4 * c];
            const float e4[4] = {ev.x, ev.y, ev.z, ev.w};
            const float a4[4] = {wa.x, wa.y, wa.z, wa.w};
            const float b4[4] = {wb.x, wb.y, wb.z, wb.w};
#pragma unroll
            for (int j = 0; j < 4; ++j)
#pragma unroll
                for (int o = 0; o < 4; ++o) {
                    acc0[j][o] = fmaf(e4[j], a4[o], acc0[j][o]);
                    acc1[j][o] = fmaf(e4[j], b4[o], acc1[j][o]);
                }
        }
#pragma unroll
        for (int o = 0; o < 4; ++o)
#pragma unroll
            for (int j = 0; j < 4; ++j) {
                hidT[(4 * c + o) * 68 + 4 * r + j]      = fmaxf(acc0[j][o], 0.f);
                hidT[(64 + 4 * c + o) * 68 + 4 * r + j] = fmaxf(acc1[j][o], 0.f);
            }
    }
    __syncthreads();

    // ---- MLP2: ff = hid W2 + b2; then x = e + ff in place into eT ----
    {
        float acc[4][4];
#pragma unroll
        for (int o = 0; o < 4; ++o) {
            const float bv = b2[4 * c + o];
#pragma unroll
            for (int j = 0; j < 4; ++j) acc[j][o] = bv;
        }
        for (int k = 0; k < 128; ++k) {
            const float4 hv = *(const float4*)&hidT[k * 68 + 4 * r];
            const float4 wv = *(const float4*)&sW2[k * 68 + 4 * c];
            const float h4[4] = {hv.x, hv.y, hv.z, hv.w};
            const float w4[4] = {wv.x, wv.y, wv.z, wv.w};
#pragma unroll
            for (int j = 0; j < 4; ++j)
#pragma unroll
                for (int o = 0; o < 4; ++o)
                    acc[j][o] = fmaf(h4[j], w4[o], acc[j][o]);
        }
#pragma unroll
        for (int o = 0; o < 4; ++o)
#pragma unroll
            for (int j = 0; j < 4; ++j)
                eT[(4 * c + o) * 68 + (4 * r + j)] += acc[j][o];
    }
    __syncthreads();

    // ---- LN stats ----
    {
        const int tk = t & 63, p = t >> 6;
        float s = 0.f, q = 0.f;
#pragma unroll
        for (int i = 0; i < 16; ++i) {
            const float x = eT[(16 * p + i) * 68 + tk];
            s += x;
            q = fmaf(x, x, q);
        }
        red1[p][tk] = s;
        red2[p][tk] = q;
    }
    __syncthreads();
    if (t < 64) {
        const float s  = ((red1[0][t] + red1[1][t]) + (red1[2][t] + red1[3][t]));
        const float qq = ((red2[0][t] + red2[1][t]) + (red2[2][t] + red2[3][t]));
        const float mu  = s * (1.0f / 64.0f);
        const float var = qq * (1.0f / 64.0f) - mu * mu;
        smu[t]   = mu;
        srstd[t] = 1.0f / sqrtf(var + LN_EPS);
    }
    __syncthreads();

    // ---- normalize, round bf16, write h; hh over ROUNDED values ----
    {
        const int tk = t >> 2, p = t & 3;
        const float mu = smu[tk], rstd = srstd[tk];
        float hh = 0.f;
        u32 pw[8];
#pragma unroll
        for (int i2 = 0; i2 < 8; ++i2) {
            const int d = 16 * p + 2 * i2;
            const float x0 = eT[(d + 0) * 68 + tk];
            const float x1 = eT[(d + 1) * 68 + tk];
            const float o0 = (x0 - mu) * rstd * gamma[d + 0] + beta[d + 0];
            const float o1 = (x1 - mu) * rstd * gamma[d + 1] + beta[d + 1];
            const u16 r0 = f2bf(o0), r1 = f2bf(o1);
            const float q0f = bf2f(r0), q1f = bf2f(r1);
            hh = fmaf(q0f, q0f, hh);
            hh = fmaf(q1f, q1f, hh);
            pw[i2] = (u32)r0 | ((u32)r1 << 16);
        }
        uint4* hp = (uint4*)(h_out + (size_t)(tok0 + tk) * HDIM + 16 * p);
        hp[0] = make_uint4(pw[0], pw[1], pw[2], pw[3]);
        hp[1] = make_uint4(pw[4], pw[5], pw[6], pw[7]);
        red1[p][tk] = hh;
    }
    __syncthreads();
    if (t < 64) {
        const float hh = ((red1[0][t] + red1[1][t]) + (red1[2][t] + red1[3][t]));
        invd_out[tok0 + t] = 1.0f / (hh + D_EPS);
    }
}

// ---------------------------------------------------------------------------
// Kernel 2: segment composition. R10: NSEG=32 / CPS=4 -> 512 blocks, half the
// serial chunks per block, and ~51 KB LDS so up to 3 blocks/CU co-reside
// (stall overlap). Zt computed inline (R9-verified bit-identical).
// ---------------------------------------------------------------------------
__global__ __launch_bounds__(256, 1) void compose_kernel(
    const u16* __restrict__ hb16, const float* __restrict__ invd,
    u32* __restrict__ PK)
{
    const int b = blockIdx.x >> 5;         // batch
    const int s = blockIdx.x & 31;         // segment
    const u16*   hbase = hb16 + (size_t)b * LSEQ * HDIM;
    const float* dbase = invd + b * LSEQ;

    __shared__ float S[64][68];
    __shared__ float V[64][68];
    __shared__ float K[16][68];
    __shared__ float Bm[16][68];
    __shared__ float Z[16][68];
    __shared__ float Gm[16][17];
    __shared__ float ivd_s[16];

    const int t = threadIdx.x;

    // init S = I, V = 0
    for (int idx = t; idx < 64 * 64; idx += 256) {
        const int m = idx >> 6, n = idx & 63;
        S[m][n] = (m == n) ? 1.0f : 0.0f;
        V[m][n] = 0.0f;
    }

    for (int cc = 0; cc < CPS; ++cc) {
        const int c = s * CPS + cc;
        __syncthreads();   // staging vs previous phase reads / init

        // ---- stage K (bf16 -> f32) and ivd ----
        {
            const int j  = t >> 4;
            const int n0 = (t & 15) * 4;
            const int sigma = 16 * c + j;
            float4 kv = make_float4(0.f, 0.f, 0.f, 0.f);
            if (sigma > 0) {
                const ushort4 raw = *(const ushort4*)(hbase + (size_t)(2047 - sigma) * HDIM + n0);
                kv.x = bf2f(raw.x); kv.y = bf2f(raw.y); kv.z = bf2f(raw.z); kv.w = bf2f(raw.w);
            }
            *(float4*)&K[j][n0] = kv;
            if (t < 16) ivd_s[t] = dbase[2047 - (16 * c + t)];
        }
        __syncthreads();

        // ---- Gram: Gm[i][j] = (k_i . k_j) * ivd_j, i > j ----
        {
            const int i = t >> 4, j = t & 15;
            if (i > j) {
                float acc = 0.f;
#pragma unroll
                for (int m = 0; m < 64; m += 4) {
                    const float4 a  = *(const float4*)&K[i][m];
                    const float4 bb = *(const float4*)&K[j][m];
                    acc += a.x * bb.x + a.y * bb.y + a.z * bb.z + a.w * bb.w;
                }
                Gm[i][j] = acc * ivd_s[j];
            }
        }
        __syncthreads();

        // ---- B: forward substitution L B = K (wave 0) ----
        if (t < 64) {
            const int n = t;
            float Breg[16];
#pragma unroll
            for (int i = 0; i < 16; ++i) {
                float acc = K[i][n];
#pragma unroll
                for (int j = 0; j < 16; ++j)
                    if (j < i) acc = fmaf(-Gm[i][j], Breg[j], acc);
                Breg[i] = acc;
                Bm[i][n] = acc;
            }
        }
        __syncthreads();

        // ---- Z = B S ----
        {
            const int i  = t & 15;
            const int n0 = (t >> 4) * 4;
            float4 z = make_float4(0.f, 0.f, 0.f, 0.f);
#pragma unroll
            for (int mq = 0; mq < 16; ++mq) {
                const float4 bq = *(const float4*)&Bm[i][mq * 4];
                const float4 s0 = *(const float4*)&S[mq * 4 + 0][n0];
                const float4 s1 = *(const float4*)&S[mq * 4 + 1][n0];
                const float4 s2 = *(const float4*)&S[mq * 4 + 2][n0];
                const float4 s3 = *(const float4*)&S[mq * 4 + 3][n0];
                z.x = fmaf(bq.x, s0.x, fmaf(bq.y, s1.x, fmaf(bq.z, s2.x, fmaf(bq.w, s3.x, z.x))));
                z.y = fmaf(bq.x, s0.y, fmaf(bq.y, s1.y, fmaf(bq.z, s2.y, fmaf(bq.w, s3.y, z.y))));
                z.z = fmaf(bq.x, s0.z, fmaf(bq.y, s1.z, fmaf(bq.z, s2.z, fmaf(bq.w, s3.z, z.z))));
                z.w = fmaf(bq.x, s0.w, fmaf(bq.y, s1.w, fmaf(bq.z, s2.w, fmaf(bq.w, s3.w, z.w))));
            }
            *(float4*)&Z[i][n0] = z;
        }
        __syncthreads();

        // ---- S -= K^T (ivd_j * Z) ; V += K^T Z  (ztq inline) ----
        {
            const int n0 = (t & 15) * 4;
            const int mh = t >> 4;
            float iv16[16];
#pragma unroll
            for (int q4 = 0; q4 < 4; ++q4) {
                const float4 v4 = *(const float4*)&ivd_s[4 * q4];
                iv16[4*q4+0] = v4.x; iv16[4*q4+1] = v4.y;
                iv16[4*q4+2] = v4.z; iv16[4*q4+3] = v4.w;
            }
            float4 sacc[4], vacc[4];
#pragma unroll
            for (int p = 0; p < 4; ++p) {
                sacc[p] = *(float4*)&S[mh + 16 * p][n0];
                vacc[p] = *(float4*)&V[mh + 16 * p][n0];
            }
#pragma unroll
            for (int j = 0; j < 16; ++j) {
                const float4 zq = *(const float4*)&Z[j][n0];
                const float iv = iv16[j];
                float4 ztq;
                ztq.x = zq.x * iv; ztq.y = zq.y * iv;
                ztq.z = zq.z * iv; ztq.w = zq.w * iv;
                const float k0 = K[j][mh];
                const float k1 = K[j][mh + 16];
                const float k2 = K[j][mh + 32];
                const float k3 = K[j][mh + 48];
                vacc[0].x = fmaf(k0, zq.x, vacc[0].x); vacc[0].y = fmaf(k0, zq.y, vacc[0].y);
                vacc[0].z = fmaf(k0, zq.z, vacc[0].z); vacc[0].w = fmaf(k0, zq.w, vacc[0].w);
                vacc[1].x = fmaf(k1, zq.x, vacc[1].x); vacc[1].y = fmaf(k1, zq.y, vacc[1].y);
                vacc[1].z = fmaf(k1, zq.z, vacc[1].z); vacc[1].w = fmaf(k1, zq.w, vacc[1].w);
                vacc[2].x = fmaf(k2, zq.x, vacc[2].x); vacc[2].y = fmaf(k2, zq.y, vacc[2].y);
                vacc[2].z = fmaf(k2, zq.z, vacc[2].z); vacc[2].w = fmaf(k2, zq.w, vacc[2].w);
                vacc[3].x = fmaf(k3, zq.x, vacc[3].x); vacc[3].y = fmaf(k3, zq.y, vacc[3].y);
                vacc[3].z = fmaf(k3, zq.z, vacc[3].z); vacc[3].w = fmaf(k3, zq.w, vacc[3].w);
                sacc[0].x = fmaf(-k0, ztq.x, sacc[0].x); sacc[0].y = fmaf(-k0, ztq.y, sacc[0].y);
                sacc[0].z = fmaf(-k0, ztq.z, sacc[0].z); sacc[0].w = fmaf(-k0, ztq.w, sacc[0].w);
                sacc[1].x = fmaf(-k1, ztq.x, sacc[1].x); sacc[1].y = fmaf(-k1, ztq.y, sacc[1].y);
                sacc[1].z = fmaf(-k1, ztq.z, sacc[1].z); sacc[1].w = fmaf(-k1, ztq.w, sacc[1].w);
                sacc[2].x = fmaf(-k2, ztq.x, sacc[2].x); sacc[2].y = fmaf(-k2, ztq.y, sacc[2].y);
                sacc[2].z = fmaf(-k2, ztq.z, sacc[2].z); sacc[2].w = fmaf(-k2, ztq.w, sacc[2].w);
                sacc[3].x = fmaf(-k3, ztq.x, sacc[3].x); sacc[3].y = fmaf(-k3, ztq.y, sacc[3].y);
                sacc[3].z = fmaf(-k3, ztq.z, sacc[3].z); sacc[3].w = fmaf(-k3, ztq.w, sacc[3].w);
            }
#pragma unroll
            for (int p = 0; p < 4; ++p) {
                *(float4*)&S[mh + 16 * p][n0] = sacc[p];
                *(float4*)&V[mh + 16 * p][n0] = vacc[p];
            }
        }
    }
    __syncthreads();

    // ---- writeback: pk[j*64+i] = pack(bf16(S[i][j]), bf16(V[i][j])) ----
    u32* pk = PK + ((size_t)(b * NSEG + s) << 12);
    for (int idx = t; idx < 4096; idx += 256) {
        const int j = idx >> 6, i = idx & 63;
        const u32 sb = ((u32)f2bf(S[i][j])) << 16;
        const u32 vb = (u32)f2bf(V[i][j]);
        pk[idx] = sb | vb;
    }
}

// ---------------------------------------------------------------------------
// Kernel 3: serial segment pass + output projection (R8 structure, NSEG=32).
// 16 blocks x 256 threads (4 waves/batch), next-segment loads prefetched.
// ---------------------------------------------------------------------------
__global__ __launch_bounds__(256, 1) void final_kernel(
    const u16* __restrict__ hb16, const u32* __restrict__ PK,
    const float* __restrict__ Wr, const float* __restrict__ br,
    const float* __restrict__ Wo, const float* __restrict__ bo,
    float* __restrict__ out)
{
    const int b    = blockIdx.x;
    const int t    = threadIdx.x;
    const int lane = t & 63;
    const int p    = t >> 6;         // wave id = j-slice

    __shared__ float psum[4][72];
    __shared__ float rl[64];
    __shared__ float cs[64], rs[64];

    rl[lane] = bf2f(hb16[(size_t)b * LSEQ * HDIM + (size_t)2047 * HDIM + lane]);

    float ctxp = 0.f;
    u32 cur[16], nxt[16];
    {
        const u32* pk0 = PK + ((size_t)(b * NSEG + 0) << 12);
#pragma unroll
        for (int jj = 0; jj < 16; ++jj)
            cur[jj] = pk0[(p * 16 + jj) * 64 + lane];
    }
    __syncthreads();

    for (int s = 0; s < NSEG; ++s) {
        const int sn = (s + 1 < NSEG) ? s + 1 : s;
        const u32* pkn = PK + ((size_t)(b * NSEG + sn) << 12);
#pragma unroll
        for (int jj = 0; jj < 16; ++jj)
            nxt[jj] = pkn[(p * 16 + jj) * 64 + lane];

        float accr = 0.f;
#pragma unroll
        for (int jj = 0; jj < 16; ++jj) {
            const u32 pv = cur[jj];
            const float Sv = __uint_as_float(pv & 0xFFFF0000u);
            const float Vv = __uint_as_float(pv << 16);
            const float rj = rl[p * 16 + jj];
            accr = fmaf(Sv, rj, accr);
            ctxp = fmaf(Vv, rj, ctxp);
        }
        psum[p][lane] = accr;
        __syncthreads();
        const float rn = (psum[0][lane] + psum[1][lane]) + (psum[2][lane] + psum[3][lane]);
        __syncthreads();
        rl[lane] = rn;

#pragma unroll
        for (int jj = 0; jj < 16; ++jj) cur[jj] = nxt[jj];
    }

    psum[p][lane] = ctxp;
    __syncthreads();
    if (t < 64)
        cs[t] = (psum[0][t] + psum[1][t]) + (psum[2][t] + psum[3][t]);
    __syncthreads();

    float rv = (p == 0) ? br[lane] : 0.f;
#pragma unroll
    for (int i = 0; i < 16; ++i)
        rv = fmaf(cs[p * 16 + i], Wr[(p * 16 + i) * HDIM + lane], rv);
    psum[p][lane] = rv;
    __syncthreads();
    if (t < 64)
        rs[t] = (psum[0][t] + psum[1][t]) + (psum[2][t] + psum[3][t]);
    __syncthreads();

    float ov = (p == 0) ? bo[lane] : 0.f;
#pragma unroll
    for (int i = 0; i < 16; ++i)
        ov = fmaf(rs[p * 16 + i], Wo[(p * 16 + i) * HDIM + lane], ov);
    psum[p][lane] = ov;
    __syncthreads();
    if (t < 64)
        out[(size_t)b * HDIM + t] = (psum[0][t] + psum[1][t]) + (psum[2][t] + psum[3][t]);
}

// ---------------------------------------------------------------------------
extern "C" void kernel_launch(void* const* d_in, const int* in_sizes, int n_in,
                              void* d_out, int out_size, void* d_ws, size_t ws_size,
                              hipStream_t stream)
{
    const int*   seq   = (const int*)  d_in[0];
    const float* embed = (const float*)d_in[1];
    const float* W1    = (const float*)d_in[2];
    const float* b1    = (const float*)d_in[3];
    const float* W2    = (const float*)d_in[4];
    const float* b2    = (const float*)d_in[5];
    const float* gamma = (const float*)d_in[6];
    const float* beta  = (const float*)d_in[7];
    const float* Wr    = (const float*)d_in[8];
    const float* br    = (const float*)d_in[9];
    const float* Wo    = (const float*)d_in[10];
    const float* bo    = (const float*)d_in[11];

    u16*   h_ws    = (u16*)d_ws;                                   // 4 MB
    float* invd_ws = (float*)(h_ws + (size_t)BATCH * LSEQ * HDIM); // 128 KB
    u32*   pk_ws   = (u32*)(invd_ws + (size_t)BATCH * LSEQ);       // 8 MB (16*32*4096 u32)
    float* outp    = (float*)d_out;

    hipLaunchKernelGGL(preprocess_kernel, dim3(BATCH * LSEQ / 64), dim3(256), 0, stream,
                       seq, embed, W1, b1, W2, b2, gamma, beta, h_ws, invd_ws);
    hipLaunchKernelGGL(compose_kernel, dim3(BATCH * NSEG), dim3(256), 0, stream,
                       h_ws, invd_ws, pk_ws);
    hipLaunchKernelGGL(final_kernel, dim3(BATCH), dim3(256), 0, stream,
                       h_ws, pk_ws, Wr, br, Wo, bo, outp);
}

// Round 11
// 139.298 us; speedup vs baseline: 1.9291x; 1.0374x over previous
//
#include <hip/hip_runtime.h>

// Problem constants
#define HDIM 64
#define LSEQ 2048
#define BATCH 16
#define LN_EPS 1e-5f
#define D_EPS 1e-6f
#define NSEG 16      // segments per batch
#define CPS 8        // chunks per segment (16 tokens each) -> 128 tokens/block

typedef unsigned short u16;
typedef unsigned int   u32;

__device__ __forceinline__ float bf2f(u16 v) {
    return __uint_as_float(((u32)v) << 16);
}
__device__ __forceinline__ u16 f2bf(float f) {   // round-to-nearest-even
    u32 u = __float_as_uint(f);
    return (u16)((u + 0x7FFFu + ((u >> 16) & 1u)) >> 16);
}

// ---------------- shared-memory overlay (bytes) ----------------
// Phase A scratch (dead after preprocess):
#define P_SW1   0        // f32[64*132]  33792
#define P_SW2   33792    // f32[128*68]  34816
#define P_ET    68608    // f32[64*68]   17408
#define P_HIDT  86016    // f32[128*68]  34816
#define P_RED1  120832   // f32[4*66]    1056
#define P_RED2  121888   // f32[4*66]    1056
#define P_SMU   122944   // f32[68]      272
#define P_SRSTD 123216   // f32[68]      272
// Persistent across phases:
#define H_ROWS  123488   // f32[128*68]  34816  (bf16-rounded h, row-major)
#define H_INVD  158304   // f32[128]     512
#define SMEM_BYTES 158816
// Compose overlays phase-A scratch:
#define C_S     0        // f32[64*68]   17408
#define C_V     17408    // f32[64*68]   17408
#define C_BM    34816    // f32[16*68]   4352
#define C_Z     39168    // f32[16*68]   4352
#define C_GM    43520    // f32[16*17]   1088
#define C_IVD   44608    // f32[16]      64

// ---------------------------------------------------------------------------
// Kernel A: fused preprocess + segment composition. 256 blocks x 256 threads,
// block = (batch b, segment s). The block's 8 chunks consume exactly tokens
// [1920-128s, 2047-128s] of batch b, so it preprocesses those 128 tokens into
// LDS (hrows, rounded-to-bf16 f32; invd from rounded h) and composes directly
// from LDS. h/invd never touch global memory. Block (b,0) exports q (token
// 2047, bf16) to q_ws, then zeroes hrows row 127 (the sigma=0 padded key).
// ---------------------------------------------------------------------------
__global__ __launch_bounds__(256, 1) void fused_pc_kernel(
    const int* __restrict__ seq, const float* __restrict__ embed,
    const float* __restrict__ W1, const float* __restrict__ b1,
    const float* __restrict__ W2, const float* __restrict__ b2,
    const float* __restrict__ gamma, const float* __restrict__ beta,
    u32* __restrict__ PK, u16* __restrict__ q_ws)
{
    __shared__ __align__(16) char smem[SMEM_BYTES];
    const int t = threadIdx.x;
    const int b = blockIdx.x >> 4;
    const int s = blockIdx.x & 15;
    const int tok0 = 1920 - 128 * s;          // first token of this block

    float* hrows  = (float*)(smem + H_ROWS);
    float* invd_l = (float*)(smem + H_INVD);

    // ======================= Phase A: preprocess ==========================
    {
        float* sW1   = (float*)(smem + P_SW1);
        float* sW2   = (float*)(smem + P_SW2);
        float* eT    = (float*)(smem + P_ET);
        float* hidT  = (float*)(smem + P_HIDT);
        float* red1  = (float*)(smem + P_RED1);
        float* red2  = (float*)(smem + P_RED2);
        float* smu   = (float*)(smem + P_SMU);
        float* srstd = (float*)(smem + P_SRSTD);

        // stage W1 (64x128, stride 132) and W2 (128x64, stride 68) once
        {
            const float4* s1 = (const float4*)W1;   // 2048 float4
#pragma unroll
            for (int q = 0; q < 8; ++q) {
                const int m = t + 256 * q;
                const int row = m >> 5, col = m & 31;
                *(float4*)&sW1[row * 132 + col * 4] = s1[m];
            }
            const float4* s2 = (const float4*)W2;   // 2048 float4
#pragma unroll
            for (int q = 0; q < 8; ++q) {
                const int m = t + 256 * q;
                const int row = m >> 4, col = m & 15;
                *(float4*)&sW2[row * 68 + col * 4] = s2[m];
            }
        }

        for (int it = 0; it < 2; ++it) {
            const int g0 = b * LSEQ + tok0 + 64 * it;   // global token base
            __syncthreads();   // W staging (it=0) / prior tile reads (it=1)

            // stage embeddings transposed: thread (tk = t>>2, p = t&3)
            {
                const int tk = t >> 2, p = t & 3;
                const int v = seq[g0 + tk];
                const float* er = embed + v * HDIM + 16 * p;
#pragma unroll
                for (int q = 0; q < 4; ++q) {
                    const float4 ev = *(const float4*)(er + 4 * q);
                    const int d = 16 * p + 4 * q;
                    eT[(d + 0) * 68 + tk] = ev.x;
                    eT[(d + 1) * 68 + tk] = ev.y;
                    eT[(d + 2) * 68 + tk] = ev.z;
                    eT[(d + 3) * 68 + tk] = ev.w;
                }
            }
            __syncthreads();

            const int r = t >> 4;   // token quad
            const int c = t & 15;   // out quad

            // MLP1: hid = relu(e W1 + b1)
            {
                float acc0[4][4], acc1[4][4];
#pragma unroll
                for (int o = 0; o < 4; ++o) {
                    const float bA = b1[4 * c + o];
                    const float bB = b1[64 + 4 * c + o];
#pragma unroll
                    for (int j = 0; j < 4; ++j) { acc0[j][o] = bA; acc1[j][o] = bB; }
                }
                for (int k = 0; k < 64; ++k) {
                    const float4 ev = *(const float4*)&eT[k * 68 + 4 * r];
                    const float4 wa = *(const float4*)&sW1[k * 132 + 4 * c];
                    const float4 wb = *(const float4*)&sW1[k * 132 + 64 + 4 * c];
                    const float e4[4] = {ev.x, ev.y, ev.z, ev.w};
                    const float a4[4] = {wa.x, wa.y, wa.z, wa.w};
                    const float b4[4] = {wb.x, wb.y, wb.z, wb.w};
#pragma unroll
                    for (int j = 0; j < 4; ++j)
#pragma unroll
                        for (int o = 0; o < 4; ++o) {
                            acc0[j][o] = fmaf(e4[j], a4[o], acc0[j][o]);
                            acc1[j][o] = fmaf(e4[j], b4[o], acc1[j][o]);
                        }
                }
#pragma unroll
                for (int o = 0; o < 4; ++o)
#pragma unroll
                    for (int j = 0; j < 4; ++j) {
                        hidT[(4 * c + o) * 68 + 4 * r + j]      = fmaxf(acc0[j][o], 0.f);
                        hidT[(64 + 4 * c + o) * 68 + 4 * r + j] = fmaxf(acc1[j][o], 0.f);
                    }
            }
            __syncthreads();

            // MLP2: ff = hid W2 + b2; x = e + ff in place into eT
            {
                float acc[4][4];
#pragma unroll
                for (int o = 0; o < 4; ++o) {
                    const float bv = b2[4 * c + o];
#pragma unroll
                    for (int j = 0; j < 4; ++j) acc[j][o] = bv;
                }
                for (int k = 0; k < 128; ++k) {
                    const float4 hv = *(const float4*)&hidT[k * 68 + 4 * r];
                    const float4 wv = *(const float4*)&sW2[k * 68 + 4 * c];
                    const float h4[4] = {hv.x, hv.y, hv.z, hv.w};
                    const float w4[4] = {wv.x, wv.y, wv.z, wv.w};
#pragma unroll
                    for (int j = 0; j < 4; ++j)
#pragma unroll
                        for (int o = 0; o < 4; ++o)
                            acc[j][o] = fmaf(h4[j], w4[o], acc[j][o]);
                }
#pragma unroll
                for (int o = 0; o < 4; ++o)
#pragma unroll
                    for (int j = 0; j < 4; ++j)
                        eT[(4 * c + o) * 68 + (4 * r + j)] += acc[j][o];
            }
            __syncthreads();

            // LN stats
            {
                const int tk = t & 63, p = t >> 6;
                float sv = 0.f, q = 0.f;
#pragma unroll
                for (int i = 0; i < 16; ++i) {
                    const float x = eT[(16 * p + i) * 68 + tk];
                    sv += x;
                    q = fmaf(x, x, q);
                }
                red1[p * 66 + tk] = sv;
                red2[p * 66 + tk] = q;
            }
            __syncthreads();
            if (t < 64) {
                const float sv = ((red1[0 * 66 + t] + red1[1 * 66 + t]) + (red1[2 * 66 + t] + red1[3 * 66 + t]));
                const float qq = ((red2[0 * 66 + t] + red2[1 * 66 + t]) + (red2[2 * 66 + t] + red2[3 * 66 + t]));
                const float mu  = sv * (1.0f / 64.0f);
                const float var = qq * (1.0f / 64.0f) - mu * mu;
                smu[t]   = mu;
                srstd[t] = 1.0f / sqrtf(var + LN_EPS);
            }
            __syncthreads();

            // normalize, round bf16, store rounded f32 into hrows; hh over
            // ROUNDED values; block (b,0) tile 1 token 63 exports q (bf16)
            {
                const int tk = t >> 2, p = t & 3;
                const float mu = smu[tk], rstd = srstd[tk];
                const int lrow = 64 * it + tk;
                float hh = 0.f;
#pragma unroll
                for (int i2 = 0; i2 < 8; ++i2) {
                    const int d = 16 * p + 2 * i2;
                    const float x0 = eT[(d + 0) * 68 + tk];
                    const float x1 = eT[(d + 1) * 68 + tk];
                    const float o0 = (x0 - mu) * rstd * gamma[d + 0] + beta[d + 0];
                    const float o1 = (x1 - mu) * rstd * gamma[d + 1] + beta[d + 1];
                    const u16 r0 = f2bf(o0), r1 = f2bf(o1);
                    const float q0f = bf2f(r0), q1f = bf2f(r1);
                    hh = fmaf(q0f, q0f, hh);
                    hh = fmaf(q1f, q1f, hh);
                    hrows[lrow * 68 + d]     = q0f;
                    hrows[lrow * 68 + d + 1] = q1f;
                    if (s == 0 && lrow == 127) {   // token 2047: export q
                        q_ws[b * 64 + d]     = r0;
                        q_ws[b * 64 + d + 1] = r1;
                    }
                }
                red1[p * 66 + tk] = hh;
            }
            __syncthreads();
            if (t < 64) {
                const float hh = ((red1[0 * 66 + t] + red1[1 * 66 + t]) + (red1[2 * 66 + t] + red1[3 * 66 + t]));
                invd_l[64 * it + t] = 1.0f / (hh + D_EPS);
            }
        }
    }
    __syncthreads();

    // zero the sigma=0 padded key (row 127 = token 2047, only segment 0)
    if (s == 0 && t < 64) hrows[127 * 68 + t] = 0.f;

    // ======================= Phase B: compose =============================
    {
        float* S     = (float*)(smem + C_S);
        float* V     = (float*)(smem + C_V);
        float* Bm    = (float*)(smem + C_BM);
        float* Z     = (float*)(smem + C_Z);
        float* Gm    = (float*)(smem + C_GM);
        float* ivd_s = (float*)(smem + C_IVD);

        // init S = I, V = 0
        for (int idx = t; idx < 64 * 64; idx += 256) {
            const int m = idx >> 6, n = idx & 63;
            S[m * 68 + n] = (m == n) ? 1.0f : 0.0f;
            V[m * 68 + n] = 0.0f;
        }

        for (int cc = 0; cc < CPS; ++cc) {
            const int base = 127 - 16 * cc;   // hrows row of solve-slot j is base-j
            __syncthreads();   // init / previous chunk reads done

            if (t < 16) ivd_s[t] = invd_l[base - t];
            __syncthreads();

            // Gram: Gm[i][j] = (k_i . k_j) * ivd_j, i > j
            {
                const int i = t >> 4, j = t & 15;
                if (i > j) {
                    const float* ra = &hrows[(base - i) * 68];
                    const float* rb = &hrows[(base - j) * 68];
                    float acc = 0.f;
#pragma unroll
                    for (int m = 0; m < 64; m += 4) {
                        const float4 a  = *(const float4*)&ra[m];
                        const float4 bb = *(const float4*)&rb[m];
                        acc += a.x * bb.x + a.y * bb.y + a.z * bb.z + a.w * bb.w;
                    }
                    Gm[i * 17 + j] = acc * ivd_s[j];
                }
            }
            __syncthreads();

            // B: forward substitution L B = K (wave 0)
            if (t < 64) {
                const int n = t;
                float Breg[16];
#pragma unroll
                for (int i = 0; i < 16; ++i) {
                    float acc = hrows[(base - i) * 68 + n];
#pragma unroll
                    for (int j = 0; j < 16; ++j)
                        if (j < i) acc = fmaf(-Gm[i * 17 + j], Breg[j], acc);
                    Breg[i] = acc;
                    Bm[i * 68 + n] = acc;
                }
            }
            __syncthreads();

            // Z = B S
            {
                const int i  = t & 15;
                const int n0 = (t >> 4) * 4;
                float4 z = make_float4(0.f, 0.f, 0.f, 0.f);
#pragma unroll
                for (int mq = 0; mq < 16; ++mq) {
                    const float4 bq = *(const float4*)&Bm[i * 68 + mq * 4];
                    const float4 s0 = *(const float4*)&S[(mq * 4 + 0) * 68 + n0];
                    const float4 s1 = *(const float4*)&S[(mq * 4 + 1) * 68 + n0];
                    const float4 s2 = *(const float4*)&S[(mq * 4 + 2) * 68 + n0];
                    const float4 s3 = *(const float4*)&S[(mq * 4 + 3) * 68 + n0];
                    z.x = fmaf(bq.x, s0.x, fmaf(bq.y, s1.x, fmaf(bq.z, s2.x, fmaf(bq.w, s3.x, z.x))));
                    z.y = fmaf(bq.x, s0.y, fmaf(bq.y, s1.y, fmaf(bq.z, s2.y, fmaf(bq.w, s3.y, z.y))));
                    z.z = fmaf(bq.x, s0.z, fmaf(bq.y, s1.z, fmaf(bq.z, s2.z, fmaf(bq.w, s3.z, z.z))));
                    z.w = fmaf(bq.x, s0.w, fmaf(bq.y, s1.w, fmaf(bq.z, s2.w, fmaf(bq.w, s3.w, z.w))));
                }
                *(float4*)&Z[i * 68 + n0] = z;
            }
            __syncthreads();

            // S -= K^T (ivd_j * Z) ; V += K^T Z   (ztq inline)
            {
                const int n0 = (t & 15) * 4;
                const int mh = t >> 4;
                float iv16[16];
#pragma unroll
                for (int q4 = 0; q4 < 4; ++q4) {
                    const float4 v4 = *(const float4*)&ivd_s[4 * q4];
                    iv16[4*q4+0] = v4.x; iv16[4*q4+1] = v4.y;
                    iv16[4*q4+2] = v4.z; iv16[4*q4+3] = v4.w;
                }
                float4 sacc[4], vacc[4];
#pragma unroll
                for (int p = 0; p < 4; ++p) {
                    sacc[p] = *(float4*)&S[(mh + 16 * p) * 68 + n0];
                    vacc[p] = *(float4*)&V[(mh + 16 * p) * 68 + n0];
                }
#pragma unroll
                for (int j = 0; j < 16; ++j) {
                    const float4 zq = *(const float4*)&Z[j * 68 + n0];
                    const float iv = iv16[j];
                    float4 ztq;
                    ztq.x = zq.x * iv; ztq.y = zq.y * iv;
                    ztq.z = zq.z * iv; ztq.w = zq.w * iv;
                    const float* kr = &hrows[(base - j) * 68];
                    const float k0 = kr[mh];
                    const float k1 = kr[mh + 16];
                    const float k2 = kr[mh + 32];
                    const float k3 = kr[mh + 48];
                    vacc[0].x = fmaf(k0, zq.x, vacc[0].x); vacc[0].y = fmaf(k0, zq.y, vacc[0].y);
                    vacc[0].z = fmaf(k0, zq.z, vacc[0].z); vacc[0].w = fmaf(k0, zq.w, vacc[0].w);
                    vacc[1].x = fmaf(k1, zq.x, vacc[1].x); vacc[1].y = fmaf(k1, zq.y, vacc[1].y);
                    vacc[1].z = fmaf(k1, zq.z, vacc[1].z); vacc[1].w = fmaf(k1, zq.w, vacc[1].w);
                    vacc[2].x = fmaf(k2, zq.x, vacc[2].x); vacc[2].y = fmaf(k2, zq.y, vacc[2].y);
                    vacc[2].z = fmaf(k2, zq.z, vacc[2].z); vacc[2].w = fmaf(k2, zq.w, vacc[2].w);
                    vacc[3].x = fmaf(k3, zq.x, vacc[3].x); vacc[3].y = fmaf(k3, zq.y, vacc[3].y);
                    vacc[3].z = fmaf(k3, zq.z, vacc[3].z); vacc[3].w = fmaf(k3, zq.w, vacc[3].w);
                    sacc[0].x = fmaf(-k0, ztq.x, sacc[0].x); sacc[0].y = fmaf(-k0, ztq.y, sacc[0].y);
                    sacc[0].z = fmaf(-k0, ztq.z, sacc[0].z); sacc[0].w = fmaf(-k0, ztq.w, sacc[0].w);
                    sacc[1].x = fmaf(-k1, ztq.x, sacc[1].x); sacc[1].y = fmaf(-k1, ztq.y, sacc[1].y);
                    sacc[1].z = fmaf(-k1, ztq.z, sacc[1].z); sacc[1].w = fmaf(-k1, ztq.w, sacc[1].w);
                    sacc[2].x = fmaf(-k2, ztq.x, sacc[2].x); sacc[2].y = fmaf(-k2, ztq.y, sacc[2].y);
                    sacc[2].z = fmaf(-k2, ztq.z, sacc[2].z); sacc[2].w = fmaf(-k2, ztq.w, sacc[2].w);
                    sacc[3].x = fmaf(-k3, ztq.x, sacc[3].x); sacc[3].y = fmaf(-k3, ztq.y, sacc[3].y);
                    sacc[3].z = fmaf(-k3, ztq.z, sacc[3].z); sacc[3].w = fmaf(-k3, ztq.w, sacc[3].w);
                }
#pragma unroll
                for (int p = 0; p < 4; ++p) {
                    *(float4*)&S[(mh + 16 * p) * 68 + n0] = sacc[p];
                    *(float4*)&V[(mh + 16 * p) * 68 + n0] = vacc[p];
                }
            }
        }
        __syncthreads();

        // writeback: pk[j*64+i] = pack(bf16(S[i][j]), bf16(V[i][j]))
        u32* pk = PK + ((size_t)(b * NSEG + s) << 12);
        for (int idx = t; idx < 4096; idx += 256) {
            const int j = idx >> 6, i = idx & 63;
            const u32 sb = ((u32)f2bf(S[i * 68 + j])) << 16;
            const u32 vb = (u32)f2bf(V[i * 68 + j]);
            pk[idx] = sb | vb;
        }
    }
}

// ---------------------------------------------------------------------------
// Kernel B: serial segment pass + output projection (R8 structure, NSEG=16).
// 16 blocks x 256 threads (4 waves/batch), next-segment loads prefetched.
// q comes from q_ws (bf16) written by fused block (b, 0).
// ---------------------------------------------------------------------------
__global__ __launch_bounds__(256, 1) void final_kernel(
    const u16* __restrict__ q_ws, const u32* __restrict__ PK,
    const float* __restrict__ Wr, const float* __restrict__ br,
    const float* __restrict__ Wo, const float* __restrict__ bo,
    float* __restrict__ out)
{
    const int b    = blockIdx.x;
    const int t    = threadIdx.x;
    const int lane = t & 63;
    const int p    = t >> 6;         // wave id = j-slice

    __shared__ float psum[4][72];
    __shared__ float rl[64];
    __shared__ float cs[64], rs[64];

    rl[lane] = bf2f(q_ws[b * 64 + lane]);

    float ctxp = 0.f;
    u32 cur[16], nxt[16];
    {
        const u32* pk0 = PK + ((size_t)(b * NSEG + 0) << 12);
#pragma unroll
        for (int jj = 0; jj < 16; ++jj)
            cur[jj] = pk0[(p * 16 + jj) * 64 + lane];
    }
    __syncthreads();

    for (int s = 0; s < NSEG; ++s) {
        const int sn = (s + 1 < NSEG) ? s + 1 : s;
        const u32* pkn = PK + ((size_t)(b * NSEG + sn) << 12);
#pragma unroll
        for (int jj = 0; jj < 16; ++jj)
            nxt[jj] = pkn[(p * 16 + jj) * 64 + lane];

        float accr = 0.f;
#pragma unroll
        for (int jj = 0; jj < 16; ++jj) {
            const u32 pv = cur[jj];
            const float Sv = __uint_as_float(pv & 0xFFFF0000u);
            const float Vv = __uint_as_float(pv << 16);
            const float rj = rl[p * 16 + jj];
            accr = fmaf(Sv, rj, accr);
            ctxp = fmaf(Vv, rj, ctxp);
        }
        psum[p][lane] = accr;
        __syncthreads();
        const float rn = (psum[0][lane] + psum[1][lane]) + (psum[2][lane] + psum[3][lane]);
        __syncthreads();
        rl[lane] = rn;

#pragma unroll
        for (int jj = 0; jj < 16; ++jj) cur[jj] = nxt[jj];
    }

    psum[p][lane] = ctxp;
    __syncthreads();
    if (t < 64)
        cs[t] = (psum[0][t] + psum[1][t]) + (psum[2][t] + psum[3][t]);
    __syncthreads();

    float rv = (p == 0) ? br[lane] : 0.f;
#pragma unroll
    for (int i = 0; i < 16; ++i)
        rv = fmaf(cs[p * 16 + i], Wr[(p * 16 + i) * HDIM + lane], rv);
    psum[p][lane] = rv;
    __syncthreads();
    if (t < 64)
        rs[t] = (psum[0][t] + psum[1][t]) + (psum[2][t] + psum[3][t]);
    __syncthreads();

    float ov = (p == 0) ? bo[lane] : 0.f;
#pragma unroll
    for (int i = 0; i < 16; ++i)
        ov = fmaf(rs[p * 16 + i], Wo[(p * 16 + i) * HDIM + lane], ov);
    psum[p][lane] = ov;
    __syncthreads();
    if (t < 64)
        out[(size_t)b * HDIM + t] = (psum[0][t] + psum[1][t]) + (psum[2][t] + psum[3][t]);
}

// ---------------------------------------------------------------------------
extern "C" void kernel_launch(void* const* d_in, const int* in_sizes, int n_in,
                              void* d_out, int out_size, void* d_ws, size_t ws_size,
                              hipStream_t stream)
{
    const int*   seq   = (const int*)  d_in[0];
    const float* embed = (const float*)d_in[1];
    const float* W1    = (const float*)d_in[2];
    const float* b1    = (const float*)d_in[3];
    const float* W2    = (const float*)d_in[4];
    const float* b2    = (const float*)d_in[5];
    const float* gamma = (const float*)d_in[6];
    const float* beta  = (const float*)d_in[7];
    const float* Wr    = (const float*)d_in[8];
    const float* br    = (const float*)d_in[9];
    const float* Wo    = (const float*)d_in[10];
    const float* bo    = (const float*)d_in[11];

    u32* pk_ws = (u32*)d_ws;                                  // 4 MB
    u16* q_ws  = (u16*)(pk_ws + (size_t)BATCH * NSEG * 4096); // 2 KB
    float* outp = (float*)d_out;

    hipLaunchKernelGGL(fused_pc_kernel, dim3(BATCH * NSEG), dim3(256), 0, stream,
                       seq, embed, W1, b1, W2, b2, gamma, beta, pk_ws, q_ws);
    hipLaunchKernelGGL(final_kernel, dim3(BATCH), dim3(256), 0, stream,
                       q_ws, pk_ws, Wr, br, Wo, bo, outp);
}